// Round 11
// baseline (20.932 us; speedup 1.0000x reference)
//
#include <hip/hip_runtime.h>

#define IMG 512
#define CH_STRIDE (IMG * IMG)   // 262144
#define STRIP 16
#define HR    30                // STRIP + 14 halo rows
#define NT    512

typedef __attribute__((ext_vector_type(8))) _Float16 half8;
typedef __attribute__((ext_vector_type(2))) _Float16 half2v;

__device__ __forceinline__ float4 fmin4(float4 a, float4 b) {
    float4 r;
    r.x = fminf(a.x, b.x); r.y = fminf(a.y, b.y);
    r.z = fminf(a.z, b.z); r.w = fminf(a.w, b.w);
    return r;
}
__device__ __forceinline__ float2 fmin2(float2 a, float2 b) {
    float2 r;
    r.x = fminf(a.x, b.x); r.y = fminf(a.y, b.y);
    return r;
}

// Fused dark channel: phase1 = channel-min + horizontal 15-min (wave van Herk,
// R8-verified) -> LDS fp16; one barrier; phase2 = vertical 15-min -> out.
// R11: STRIP=16 / 512-thread blocks -> 512 blocks = 2-3 per CU (inter-block
// overlap hides barrier drain + store tail). Low-VGPR float2 phase 2.
__global__ __launch_bounds__(NT, 4)
void dark_fused(const float* __restrict__ x, float* __restrict__ out) {
    __shared__ _Float16 hm[HR][IMG];   // 30720 B

    const int tid  = threadIdx.x;
    const int wave = tid >> 6;         // 0..7
    const int lane = tid & 63;

    // XCD swizzle: 512 blocks, 8 XCDs -> 64 blocks/XCD = 2 images/XCD.
    const int bid   = blockIdx.x;          // 0..511
    const int q     = bid >> 3;            // 0..63
    const int img   = 2 * (bid & 7) + (q >> 5);
    const int strip = q & 31;              // 0..31
    const int r0    = strip * STRIP - 7;

    const float* xb = x + img * 3 * CH_STRIDE;

    // ---- phase 1: 30 halo rows, one row per wave-iteration ----
    for (int j = wave; j < HR; j += 8) {
        int gr = r0 + j;
        gr = gr < 0 ? -gr : (gr > IMG - 1 ? 2 * (IMG - 1) - gr : gr);
        const float* p = xb + gr * IMG + 8 * lane;

        float4 a0 = *(const float4*)(p),                 a1 = *(const float4*)(p + 4);
        float4 b0 = *(const float4*)(p + CH_STRIDE),     b1 = *(const float4*)(p + CH_STRIDE + 4);
        float4 c0 = *(const float4*)(p + 2 * CH_STRIDE), c1 = *(const float4*)(p + 2 * CH_STRIDE + 4);
        float4 v0 = fmin4(fmin4(a0, b0), c0);
        float4 v1 = fmin4(fmin4(a1, b1), c1);

        float w0 = v0.x, w1 = v0.y, w2 = v0.z, w3 = v0.w;
        float w4 = v1.x, w5 = v1.y, w6 = v1.z, w7 = v1.w;

        float P1 = fminf(w0, w1), P2 = fminf(P1, w2), P3 = fminf(P2, w3),
              P4 = fminf(P3, w4), P5 = fminf(P4, w5), P6 = fminf(P5, w6),
              M  = fminf(P6, w7);
        float S6 = fminf(w7, w6), S5 = fminf(S6, w5), S4 = fminf(S5, w4),
              S3 = fminf(S4, w3), S2 = fminf(S3, w2), S1 = fminf(S2, w1);

        float SL1 = __shfl_up(S1, 1), SL2 = __shfl_up(S2, 1), SL3 = __shfl_up(S3, 1),
              SL4 = __shfl_up(S4, 1), SL5 = __shfl_up(S5, 1), SL6 = __shfl_up(S6, 1),
              SL7 = __shfl_up(w7, 1);
        float PR0 = __shfl_down(w0, 1), PR1 = __shfl_down(P1, 1), PR2 = __shfl_down(P2, 1),
              PR3 = __shfl_down(P3, 1), PR4 = __shfl_down(P4, 1), PR5 = __shfl_down(P5, 1),
              PR6 = __shfl_down(P6, 1);

        // out[k] = min(SL[k+1], M, PR[k-1]); lanes 0/63 self-shfl = exact reflect
        half8 hv;
        hv[0] = (_Float16)fminf(SL1, M);
        hv[1] = (_Float16)fminf(SL2, fminf(M, PR0));
        hv[2] = (_Float16)fminf(SL3, fminf(M, PR1));
        hv[3] = (_Float16)fminf(SL4, fminf(M, PR2));
        hv[4] = (_Float16)fminf(SL5, fminf(M, PR3));
        hv[5] = (_Float16)fminf(SL6, fminf(M, PR4));
        hv[6] = (_Float16)fminf(SL7, fminf(M, PR5));
        hv[7] = (_Float16)fminf(M, PR6);
        *(half8*)&hm[j][8 * lane] = hv;
    }
    __syncthreads();

    // ---- phase 2: vertical 15-min from LDS (float2 x 8 rows, low VGPR) ----
    // thread -> 2 cols (c2) x 8 out rows (jb..jb+7); hm rows jb .. jb+21
    const int c2 = tid & 255;         // col pair: cols 2*c2, 2*c2+1
    const int jb = (tid >> 8) * 8;    // 0 or 8

    float2 w[22];
    #pragma unroll
    for (int i = 0; i < 22; ++i) {
        half2v h = *(half2v*)&hm[jb + i][2 * c2];
        w[i] = make_float2((float)h[0], (float)h[1]);
    }

    // suffix min: w[i] = min(orig w[i..14]) for i<=14
    #pragma unroll
    for (int i = 13; i >= 0; --i) w[i] = fmin2(w[i], w[i + 1]);

    float* ob = out + img * CH_STRIDE + (strip * STRIP + jb) * IMG + 2 * c2;
    *(float2*)(ob) = w[0];
    float2 pr = w[15];
    #pragma unroll
    for (int k = 1; k < 8; ++k) {
        *(float2*)(ob + k * IMG) = fmin2(w[k], pr);
        if (k < 7) pr = fmin2(pr, w[15 + k]);
    }
}

extern "C" void kernel_launch(void* const* d_in, const int* in_sizes, int n_in,
                              void* d_out, int out_size, void* d_ws, size_t ws_size,
                              hipStream_t stream) {
    const float* x = (const float*)d_in[0];
    float* out = (float*)d_out;
    dark_fused<<<dim3(512), dim3(NT), 0, stream>>>(x, out);
}

// Round 12
// 16.980 us; speedup vs baseline: 1.2327x; 1.2327x over previous
//
#include <hip/hip_runtime.h>

#define IMG 512
#define CH_STRIDE (IMG * IMG)   // 262144
#define STRIP 32
#define HR    46                // STRIP + 14 halo rows
#define NT    1024

typedef __attribute__((ext_vector_type(8))) _Float16 half8;
typedef __attribute__((ext_vector_type(4))) _Float16 half4;

__device__ __forceinline__ float4 fmin4(float4 a, float4 b) {
    float4 r;
    r.x = fminf(a.x, b.x); r.y = fminf(a.y, b.y);
    r.z = fminf(a.z, b.z); r.w = fminf(a.w, b.w);
    return r;
}

// R8-verified wave van Herk over one row: 6 channel float4s (8 cols/lane)
// -> horizontal-15-min as half8. Lanes 0/63 self-shfl = exact reflect.
__device__ __forceinline__ half8 hrow(float4 a0, float4 a1, float4 b0, float4 b1,
                                      float4 c0, float4 c1) {
    float4 v0 = fmin4(fmin4(a0, b0), c0);
    float4 v1 = fmin4(fmin4(a1, b1), c1);
    float w0 = v0.x, w1 = v0.y, w2 = v0.z, w3 = v0.w;
    float w4 = v1.x, w5 = v1.y, w6 = v1.z, w7 = v1.w;

    float P1 = fminf(w0, w1), P2 = fminf(P1, w2), P3 = fminf(P2, w3),
          P4 = fminf(P3, w4), P5 = fminf(P4, w5), P6 = fminf(P5, w6),
          M  = fminf(P6, w7);
    float S6 = fminf(w7, w6), S5 = fminf(S6, w5), S4 = fminf(S5, w4),
          S3 = fminf(S4, w3), S2 = fminf(S3, w2), S1 = fminf(S2, w1);

    float SL1 = __shfl_up(S1, 1), SL2 = __shfl_up(S2, 1), SL3 = __shfl_up(S3, 1),
          SL4 = __shfl_up(S4, 1), SL5 = __shfl_up(S5, 1), SL6 = __shfl_up(S6, 1),
          SL7 = __shfl_up(w7, 1);
    float PR0 = __shfl_down(w0, 1), PR1 = __shfl_down(P1, 1), PR2 = __shfl_down(P2, 1),
          PR3 = __shfl_down(P3, 1), PR4 = __shfl_down(P4, 1), PR5 = __shfl_down(P5, 1),
          PR6 = __shfl_down(P6, 1);

    half8 hv;
    hv[0] = (_Float16)fminf(SL1, M);
    hv[1] = (_Float16)fminf(SL2, fminf(M, PR0));
    hv[2] = (_Float16)fminf(SL3, fminf(M, PR1));
    hv[3] = (_Float16)fminf(SL4, fminf(M, PR2));
    hv[4] = (_Float16)fminf(SL5, fminf(M, PR3));
    hv[5] = (_Float16)fminf(SL6, fminf(M, PR4));
    hv[6] = (_Float16)fminf(SL7, fminf(M, PR5));
    hv[7] = (_Float16)fminf(M, PR6);
    return hv;
}

__device__ __forceinline__ int reflect_idx(int i) {
    i = i < 0 ? -i : i;
    return i > IMG - 1 ? 2 * (IMG - 1) - i : i;
}

// Fused dark channel. R12 = R10 + phase-1 full unroll with all 18 loads
// hoisted (MLP 6 -> 18 outstanding loads/wave). Everything else identical.
__global__ __launch_bounds__(NT)
void dark_fused(const float* __restrict__ x, float* __restrict__ out) {
    __shared__ _Float16 hm[HR][IMG];   // 47104 B

    const int tid  = threadIdx.x;
    const int wave = tid >> 6;         // 0..15
    const int lane = tid & 63;

    // XCD swizzle: all 16 strips of an image share one XCD (L2 halo reuse).
    const int bid   = blockIdx.x;          // 0..255
    const int img   = 2 * (bid & 7) + (bid >> 7);
    const int strip = (bid >> 3) & 15;
    const int r0    = strip * STRIP - 7;

    const float* xb = x + img * 3 * CH_STRIDE;

    // ---- phase 1: rows wave, wave+16, wave+32; all loads issued up front ----
    const int j0 = wave, j1 = wave + 16, j2 = wave + 32;   // j2 valid if wave<14
    const float* p0 = xb + reflect_idx(r0 + j0) * IMG + 8 * lane;
    const float* p1 = xb + reflect_idx(r0 + j1) * IMG + 8 * lane;
    const float* p2 = xb + reflect_idx(r0 + j2) * IMG + 8 * lane;  // in-bounds even if j2>=HR

    float4 a00 = *(const float4*)(p0),                 a01 = *(const float4*)(p0 + 4);
    float4 b00 = *(const float4*)(p0 + CH_STRIDE),     b01 = *(const float4*)(p0 + CH_STRIDE + 4);
    float4 c00 = *(const float4*)(p0 + 2 * CH_STRIDE), c01 = *(const float4*)(p0 + 2 * CH_STRIDE + 4);
    float4 a10 = *(const float4*)(p1),                 a11 = *(const float4*)(p1 + 4);
    float4 b10 = *(const float4*)(p1 + CH_STRIDE),     b11 = *(const float4*)(p1 + CH_STRIDE + 4);
    float4 c10 = *(const float4*)(p1 + 2 * CH_STRIDE), c11 = *(const float4*)(p1 + 2 * CH_STRIDE + 4);
    float4 a20 = *(const float4*)(p2),                 a21 = *(const float4*)(p2 + 4);
    float4 b20 = *(const float4*)(p2 + CH_STRIDE),     b21 = *(const float4*)(p2 + CH_STRIDE + 4);
    float4 c20 = *(const float4*)(p2 + 2 * CH_STRIDE), c21 = *(const float4*)(p2 + 2 * CH_STRIDE + 4);

    *(half8*)&hm[j0][8 * lane] = hrow(a00, a01, b00, b01, c00, c01);
    *(half8*)&hm[j1][8 * lane] = hrow(a10, a11, b10, b11, c10, c11);
    half8 h2 = hrow(a20, a21, b20, b21, c20, c21);
    if (j2 < HR) *(half8*)&hm[j2][8 * lane] = h2;
    __syncthreads();

    // ---- phase 2: vertical 15-min from LDS (unchanged from R10) ----
    const int c4 = tid & 127;
    const int jb = (tid >> 7) * 4;    // 0,4,...,28

    float4 w[18];
    #pragma unroll
    for (int i = 0; i < 18; ++i) {
        half4 h = *(half4*)&hm[jb + i][4 * c4];
        w[i] = make_float4((float)h[0], (float)h[1], (float)h[2], (float)h[3]);
    }

    float4 ca = fmin4(fmin4(w[3],  w[4]),  fmin4(w[5],  w[6]));
    float4 cb = fmin4(fmin4(w[7],  w[8]),  fmin4(w[9],  w[10]));
    float4 cc = fmin4(fmin4(w[11], w[12]), fmin4(w[13], w[14]));
    float4 common = fmin4(ca, fmin4(cb, cc));
    float4 p01 = fmin4(w[1], w[2]);
    float4 s01 = fmin4(w[15], w[16]);

    float* ob = out + img * CH_STRIDE + (strip * STRIP + jb) * IMG + 4 * c4;
    *(float4*)(ob)           = fmin4(fmin4(w[0], p01), common);
    *(float4*)(ob + IMG)     = fmin4(fmin4(p01, w[15]), common);
    *(float4*)(ob + 2 * IMG) = fmin4(fmin4(w[2], s01), common);
    *(float4*)(ob + 3 * IMG) = fmin4(fmin4(s01, w[17]), common);
}

extern "C" void kernel_launch(void* const* d_in, const int* in_sizes, int n_in,
                              void* d_out, int out_size, void* d_ws, size_t ws_size,
                              hipStream_t stream) {
    const float* x = (const float*)d_in[0];
    float* out = (float*)d_out;
    dark_fused<<<dim3(256), dim3(NT), 0, stream>>>(x, out);
}

// Round 13
// 16.841 us; speedup vs baseline: 1.2429x; 1.0082x over previous
//
#include <hip/hip_runtime.h>

#define IMG 512
#define CH_STRIDE (IMG * IMG)   // 262144
#define STRIP 32
#define HR    46                // STRIP + 14 halo rows
#define NT    1024

typedef __attribute__((ext_vector_type(8))) _Float16 half8;
typedef __attribute__((ext_vector_type(4))) _Float16 half4;

__device__ __forceinline__ float4 fmin4(float4 a, float4 b) {
    float4 r;
    r.x = fminf(a.x, b.x); r.y = fminf(a.y, b.y);
    r.z = fminf(a.z, b.z); r.w = fminf(a.w, b.w);
    return r;
}

__device__ __forceinline__ half4 hmin4(half4 a, half4 b) {
    return __builtin_elementwise_min(a, b);   // v_pk_min_f16 x2
}

// R8-verified wave van Herk over one row: 6 channel float4s (8 cols/lane)
// -> horizontal-15-min as half8. Lanes 0/63 self-shfl = exact reflect.
__device__ __forceinline__ half8 hrow(float4 a0, float4 a1, float4 b0, float4 b1,
                                      float4 c0, float4 c1) {
    float4 v0 = fmin4(fmin4(a0, b0), c0);
    float4 v1 = fmin4(fmin4(a1, b1), c1);
    float w0 = v0.x, w1 = v0.y, w2 = v0.z, w3 = v0.w;
    float w4 = v1.x, w5 = v1.y, w6 = v1.z, w7 = v1.w;

    float P1 = fminf(w0, w1), P2 = fminf(P1, w2), P3 = fminf(P2, w3),
          P4 = fminf(P3, w4), P5 = fminf(P4, w5), P6 = fminf(P5, w6),
          M  = fminf(P6, w7);
    float S6 = fminf(w7, w6), S5 = fminf(S6, w5), S4 = fminf(S5, w4),
          S3 = fminf(S4, w3), S2 = fminf(S3, w2), S1 = fminf(S2, w1);

    float SL1 = __shfl_up(S1, 1), SL2 = __shfl_up(S2, 1), SL3 = __shfl_up(S3, 1),
          SL4 = __shfl_up(S4, 1), SL5 = __shfl_up(S5, 1), SL6 = __shfl_up(S6, 1),
          SL7 = __shfl_up(w7, 1);
    float PR0 = __shfl_down(w0, 1), PR1 = __shfl_down(P1, 1), PR2 = __shfl_down(P2, 1),
          PR3 = __shfl_down(P3, 1), PR4 = __shfl_down(P4, 1), PR5 = __shfl_down(P5, 1),
          PR6 = __shfl_down(P6, 1);

    half8 hv;
    hv[0] = (_Float16)fminf(SL1, M);
    hv[1] = (_Float16)fminf(SL2, fminf(M, PR0));
    hv[2] = (_Float16)fminf(SL3, fminf(M, PR1));
    hv[3] = (_Float16)fminf(SL4, fminf(M, PR2));
    hv[4] = (_Float16)fminf(SL5, fminf(M, PR3));
    hv[5] = (_Float16)fminf(SL6, fminf(M, PR4));
    hv[6] = (_Float16)fminf(SL7, fminf(M, PR5));
    hv[7] = (_Float16)fminf(M, PR6);
    return hv;
}

__device__ __forceinline__ int reflect_idx(int i) {
    i = i < 0 ? -i : i;
    return i > IMG - 1 ? 2 * (IMG - 1) - i : i;
}

// Fused dark channel. R13 = R12 with phase 2 entirely in packed fp16
// (v_pk_min_f16), fp32 conversion only at the final store.
__global__ __launch_bounds__(NT)
void dark_fused(const float* __restrict__ x, float* __restrict__ out) {
    __shared__ _Float16 hm[HR][IMG];   // 47104 B

    const int tid  = threadIdx.x;
    const int wave = tid >> 6;         // 0..15
    const int lane = tid & 63;

    // XCD swizzle: all 16 strips of an image share one XCD (L2 halo reuse).
    const int bid   = blockIdx.x;          // 0..255
    const int img   = 2 * (bid & 7) + (bid >> 7);
    const int strip = (bid >> 3) & 15;
    const int r0    = strip * STRIP - 7;

    const float* xb = x + img * 3 * CH_STRIDE;

    // ---- phase 1: rows wave, wave+16, wave+32; all 18 loads issued up front ----
    const int j0 = wave, j1 = wave + 16, j2 = wave + 32;   // j2 valid if wave<14
    const float* p0 = xb + reflect_idx(r0 + j0) * IMG + 8 * lane;
    const float* p1 = xb + reflect_idx(r0 + j1) * IMG + 8 * lane;
    const float* p2 = xb + reflect_idx(r0 + j2) * IMG + 8 * lane;  // addr in-bounds always

    float4 a00 = *(const float4*)(p0),                 a01 = *(const float4*)(p0 + 4);
    float4 b00 = *(const float4*)(p0 + CH_STRIDE),     b01 = *(const float4*)(p0 + CH_STRIDE + 4);
    float4 c00 = *(const float4*)(p0 + 2 * CH_STRIDE), c01 = *(const float4*)(p0 + 2 * CH_STRIDE + 4);
    float4 a10 = *(const float4*)(p1),                 a11 = *(const float4*)(p1 + 4);
    float4 b10 = *(const float4*)(p1 + CH_STRIDE),     b11 = *(const float4*)(p1 + CH_STRIDE + 4);
    float4 c10 = *(const float4*)(p1 + 2 * CH_STRIDE), c11 = *(const float4*)(p1 + 2 * CH_STRIDE + 4);
    float4 a20 = *(const float4*)(p2),                 a21 = *(const float4*)(p2 + 4);
    float4 b20 = *(const float4*)(p2 + CH_STRIDE),     b21 = *(const float4*)(p2 + CH_STRIDE + 4);
    float4 c20 = *(const float4*)(p2 + 2 * CH_STRIDE), c21 = *(const float4*)(p2 + 2 * CH_STRIDE + 4);

    *(half8*)&hm[j0][8 * lane] = hrow(a00, a01, b00, b01, c00, c01);
    *(half8*)&hm[j1][8 * lane] = hrow(a10, a11, b10, b11, c10, c11);
    half8 h2 = hrow(a20, a21, b20, b21, c20, c21);
    if (j2 < HR) *(half8*)&hm[j2][8 * lane] = h2;
    __syncthreads();

    // ---- phase 2: vertical 15-min in packed fp16 (exact on stored values) ----
    const int c4 = tid & 127;
    const int jb = (tid >> 7) * 4;    // 0,4,...,28

    half4 w[18];
    #pragma unroll
    for (int i = 0; i < 18; ++i) w[i] = *(half4*)&hm[jb + i][4 * c4];

    half4 ca = hmin4(hmin4(w[3],  w[4]),  hmin4(w[5],  w[6]));
    half4 cb = hmin4(hmin4(w[7],  w[8]),  hmin4(w[9],  w[10]));
    half4 cc = hmin4(hmin4(w[11], w[12]), hmin4(w[13], w[14]));
    half4 common = hmin4(ca, hmin4(cb, cc));
    half4 p01 = hmin4(w[1], w[2]);
    half4 s01 = hmin4(w[15], w[16]);

    half4 o0 = hmin4(hmin4(w[0], p01), common);
    half4 o1 = hmin4(hmin4(p01, w[15]), common);
    half4 o2 = hmin4(hmin4(w[2], s01), common);
    half4 o3 = hmin4(hmin4(s01, w[17]), common);

    float* ob = out + img * CH_STRIDE + (strip * STRIP + jb) * IMG + 4 * c4;
    *(float4*)(ob)           = make_float4((float)o0[0], (float)o0[1], (float)o0[2], (float)o0[3]);
    *(float4*)(ob + IMG)     = make_float4((float)o1[0], (float)o1[1], (float)o1[2], (float)o1[3]);
    *(float4*)(ob + 2 * IMG) = make_float4((float)o2[0], (float)o2[1], (float)o2[2], (float)o2[3]);
    *(float4*)(ob + 3 * IMG) = make_float4((float)o3[0], (float)o3[1], (float)o3[2], (float)o3[3]);
}

extern "C" void kernel_launch(void* const* d_in, const int* in_sizes, int n_in,
                              void* d_out, int out_size, void* d_ws, size_t ws_size,
                              hipStream_t stream) {
    const float* x = (const float*)d_in[0];
    float* out = (float*)d_out;
    dark_fused<<<dim3(256), dim3(NT), 0, stream>>>(x, out);
}